// Round 7
// baseline (6981.162 us; speedup 1.0000x reference)
//
#include <hip/hip_runtime.h>

#define N_CLOUDS 16
#define PTS      16384
#define M        4096
#define THREADS  1024
#define NWAVES   16
#define PPT      16                 // consecutive points per thread

typedef float v2f __attribute__((ext_vector_type(2)));
typedef unsigned long long u64;
typedef unsigned int u32;

// One block per cloud; serial FPS. Round-7 synthesis of what rounds 3-6 proved:
//  - 16 pts/thread => 64 floats of loop state: genuinely fits in 128-VGPR
//    budget at 4 waves/SIMD (R5's 32/thread never could -> AGPR tax; R6's
//    LDS streaming paid unhideable ds_read latency at 2 waves/SIMD).
//  - asm "+v" pin on coords blocks the R4 remat-reload disease.
//  - f32 value-only wave reduce via DPP (8 inst, not 45 for u64 keys);
//    per-pair argmax tracking folded into update as v_max3 partial maxes.
//  - winner index AND all 3 coords recovered via candidate scan + 3 LDS
//    atomicMin keys (idx<<32 | coord bits): min idx wins all three => tie-safe
//    (first-occurrence argmax), and no global coord fetch on the serial tail.
//  - 2 barriers/iter; mins slots rotate mod 4, re-armed 2 iters ahead.
//  - contract-off exact math (absmax=0 in rounds 2-6).

#define PAIRS_X(X) X(0) X(1) X(2) X(3) X(4) X(5) X(6) X(7)
#define F12_X(X) X(0) X(1) X(2) X(3) X(4) X(5) X(6) X(7) X(8) X(9) X(10) X(11)
// QUAD(j0,j1,a,b,c): pairs j0=2m, j1=2m+1 from float4 f_a,f_b,f_c
// (points 4m..4m+3 = 12 floats: x0 y0 z0 x1 y1 z1 x2 y2 z2 x3 y3 z3)
#define QUADS_X(X) X(0,1,0,1,2) X(2,3,3,4,5) X(4,5,6,7,8) X(6,7,9,10,11)

// f32 max-combine with DPP-shifted copy (old=0 = +0.0f, identity: dists >= 0)
#define DPP_FMAX(bd, CTRL) { \
        const int t_ = __builtin_amdgcn_update_dpp(0, __float_as_int(bd), (CTRL), 0xf, 0xf, false); \
        (bd) = fmaxf((bd), __int_as_float(t_)); }

__global__ __launch_bounds__(THREADS) void fps_kernel(
    const float* __restrict__ pos, int* __restrict__ out)
{
#pragma clang fp contract(off)
    __shared__ float swv[NWAVES];   // per-wave maxes
    __shared__ u64   mins[4 * 3];   // 4 rotating slots x {xkey, ykey, zkey}

    const int cloud = blockIdx.x;
    const int tid   = threadIdx.x;
    const int base  = cloud * PTS;

    // ---- query = point 0 of cloud ----
    const float q0x = pos[(size_t)base * 3 + 0];
    const float q0y = pos[(size_t)base * 3 + 1];
    const float q0z = pos[(size_t)base * 3 + 2];
    v2f qx2 = {q0x, q0x}, qy2 = {q0y, q0y}, qz2 = {q0z, q0z};

    // ---- one-time load: 16 consecutive pts = 12 float4/thread ----
    const float4* pos4 = (const float4*)pos;
    const int fo = cloud * (PTS * 3 / 4) + tid * (PPT * 3 / 4);
#define LOADF(n) const float4 f##n = pos4[fo + (n)];
    F12_X(LOADF)
#undef LOADF

    // ---- register state: 8 v2f per coord + 8 v2f dists = 64 floats ----
#define DECL(j) v2f XX##j, YY##j, ZZ##j, dd##j;
    PAIRS_X(DECL)
#undef DECL
#define REPACK(j0, j1, a, b, c) \
        XX##j0 = (v2f){f##a.x, f##a.w}; \
        YY##j0 = (v2f){f##a.y, f##b.x}; \
        ZZ##j0 = (v2f){f##a.z, f##b.y}; \
        XX##j1 = (v2f){f##b.z, f##c.y}; \
        YY##j1 = (v2f){f##b.w, f##c.z}; \
        ZZ##j1 = (v2f){f##c.x, f##c.w};
    QUADS_X(REPACK)
#undef REPACK

    // ---- pin coords in VGPRs: opaque defs => no remat-reload ----
#define PIN8(a,b,c,d,e,g,h,k) asm volatile("" : "+v"(a),"+v"(b),"+v"(c),"+v"(d),"+v"(e),"+v"(g),"+v"(h),"+v"(k));
    PIN8(XX0, XX1, XX2, XX3, XX4, XX5, XX6, XX7)
    PIN8(YY0, YY1, YY2, YY3, YY4, YY5, YY6, YY7)
    PIN8(ZZ0, ZZ1, ZZ2, ZZ3, ZZ4, ZZ5, ZZ6, ZZ7)
#undef PIN8

    // ---- init dists to point 0; partial maxes bd0 (pairs 0-3), bd1 (4-7) ----
    float bd0 = -1.0f, bd1 = -1.0f;
#define INITP(j, BD) { \
        v2f dx = XX##j - qx2; \
        v2f dy = YY##j - qy2; \
        v2f dz = ZZ##j - qz2; \
        v2f nd = (dx * dx + dy * dy) + dz * dz; \
        dd##j = nd; \
        BD = fmaxf(fmaxf(nd.x, nd.y), BD); }
    INITP(0, bd0) INITP(1, bd0) INITP(2, bd0) INITP(3, bd0)
    INITP(4, bd1) INITP(5, bd1) INITP(6, bd1) INITP(7, bd1)
#undef INITP

    if (tid < 12) mins[tid] = ~0ull;       // arm all 4 slots
    if (tid == 0) out[cloud * M] = base;   // first sample = point 0

    const int wave = tid >> 6;
    const int lane = tid & 63;

    for (int i = 1; i < M; ++i) {
        const int s = (i & 3) * 3;

        // ---- wave f32 max via DPP; lane 63 = wave max ----
        float bd = fmaxf(bd0, bd1);
        DPP_FMAX(bd, 0x111)   // row_shr:1
        DPP_FMAX(bd, 0x112)   // row_shr:2
        DPP_FMAX(bd, 0x114)   // row_shr:4
        DPP_FMAX(bd, 0x118)   // row_shr:8
        DPP_FMAX(bd, 0x142)   // row_bcast:15
        DPP_FMAX(bd, 0x143)   // row_bcast:31 -> lane 63 = wave max
        if (lane == 63) swv[wave] = bd;
        __syncthreads();                              // B1: swv + mins visible

        // ---- block max: 16 wave maxes in lanes, 4 DPP steps, readlane 15 ----
        float wvv = swv[lane & 15];
        DPP_FMAX(wvv, 0x111)
        DPP_FMAX(wvv, 0x112)
        DPP_FMAX(wvv, 0x114)
        DPP_FMAX(wvv, 0x118)   // lane 15 (each row) = max of all 16
        const float wv = __int_as_float(
            __builtin_amdgcn_readlane(__float_as_int(wvv), 15));  // uniform

        // ---- candidate scan: only first candidate lane of candidate waves ----
        const bool c0 = (bd0 == wv);
        const bool c1 = (bd1 == wv);
        const u64 bal = __ballot(c0 || c1);
        if ((c0 || c1) && lane == (__ffsll(bal) - 1)) {
            int k = 0; float xs = 0.0f, ys = 0.0f, zs = 0.0f;
#define SCANJ(j) { if (dd##j.y == wv) { k = 2*(j)+1; xs = XX##j.y; ys = YY##j.y; zs = ZZ##j.y; } \
                   if (dd##j.x == wv) { k = 2*(j);   xs = XX##j.x; ys = YY##j.x; zs = ZZ##j.x; } }
            if (c0) { SCANJ(3) SCANJ(2) SCANJ(1) SCANJ(0) }
            else    { SCANJ(7) SCANJ(6) SCANJ(5) SCANJ(4) }
#undef SCANJ
            const u64 hi = (u64)(u32)(tid * PPT + k) << 32;
            atomicMin(&mins[s + 0], hi | __float_as_uint(xs));
            atomicMin(&mins[s + 1], hi | __float_as_uint(ys));
            atomicMin(&mins[s + 2], hi | __float_as_uint(zs));
        }
        __syncthreads();                              // B2: mins resolved

        // ---- winner idx + coords straight from the min-keys ----
        const u64 wkx = mins[s + 0];
        const u64 wky = mins[s + 1];
        const u64 wkz = mins[s + 2];
        const int wi  = (int)(wkx >> 32);
        const float qx = __uint_as_float((u32)wkx);
        const float qy = __uint_as_float((u32)wky);
        const float qz = __uint_as_float((u32)wkz);
        if (tid == 0) {
            out[cloud * M + i] = base + wi;
            const int s2 = ((i + 2) & 3) * 3;         // re-arm slot for iter i+2
            mins[s2 + 0] = ~0ull; mins[s2 + 1] = ~0ull; mins[s2 + 2] = ~0ull;
        }
        qx2 = (v2f){qx, qx}; qy2 = (v2f){qy, qy}; qz2 = (v2f){qz, qz};

        // ---- distance update + folded partial-max tracking ----
        bd0 = -1.0f; bd1 = -1.0f;
#define UPD(j, BD) { \
        v2f dx = XX##j - qx2; \
        v2f dy = YY##j - qy2; \
        v2f dz = ZZ##j - qz2; \
        v2f nd = (dx * dx + dy * dy) + dz * dz; \
        dd##j.x = fminf(dd##j.x, nd.x); \
        dd##j.y = fminf(dd##j.y, nd.y); \
        BD = fmaxf(fmaxf(dd##j.x, dd##j.y), BD); }
        UPD(0, bd0) UPD(1, bd0) UPD(2, bd0) UPD(3, bd0)
        UPD(4, bd1) UPD(5, bd1) UPD(6, bd1) UPD(7, bd1)
#undef UPD
    }
}

extern "C" void kernel_launch(void* const* d_in, const int* in_sizes, int n_in,
                              void* d_out, int out_size, void* d_ws, size_t ws_size,
                              hipStream_t stream) {
    const float* pos = (const float*)d_in[0];
    int* out = (int*)d_out;
    fps_kernel<<<N_CLOUDS, THREADS, 0, stream>>>(pos, out);
}